// Round 2
// baseline (209.935 us; speedup 1.0000x reference)
//
#include <hip/hip_runtime.h>
#include <stdint.h>

#define T 4096
#define E 64
#define NBH 32
#define NWIN 32                 // T / 128 windows
#define LDK 136                 // [K|Kr] row stride (shorts): 16B-aligned, 2-way banks max
#define LDV 72                  // Vt row stride (shorts)
#define LDP 72                  // P scratch row stride (shorts)
#define KK_ELEMS (64*LDK)       // 8704 elems
#define VT_ELEMS (64*LDV)       // 4608 elems
#define BUF_ELEMS (KK_ELEMS+VT_ELEMS)   // 13312 elems = 26624 B
#define PW_ELEMS (16*LDP)       // 1152 elems
#define SMEM_BYTES ((2*BUF_ELEMS + 8*PW_ELEMS)*2)   // 71680 B -> 2 blocks/CU

typedef __attribute__((ext_vector_type(8))) short short8;
typedef __attribute__((ext_vector_type(4))) short short4v;
typedef __attribute__((ext_vector_type(4))) float f32x4;

__device__ __forceinline__ short f2bf(float x) {
  unsigned u = __float_as_uint(x);
  u += 0x7fffu + ((u >> 16) & 1u);   // round-to-nearest-even
  return (short)(u >> 16);
}

// barrier without vmcnt drain (staged global loads stay in flight)
__device__ __forceinline__ void block_sync_lds() {
  asm volatile("s_waitcnt lgkmcnt(0)" ::: "memory");
  __builtin_amdgcn_s_barrier();
  asm volatile("" ::: "memory");
}

// staging registers for one 64-key sub-tile of K/Kr/V
struct SubStage { float4 sk[4]; float sv[8]; };

__device__ __forceinline__ void sub_issue(SubStage& st,
    const float* __restrict__ k, const float* __restrict__ kr,
    const float* __restrict__ v, size_t rowbase, int tid, int wid, int lane) {
#pragma unroll
  for (int m = 0; m < 2; ++m) {
    const float* src = m ? kr : k;
#pragma unroll
    for (int it = 0; it < 2; ++it) {
      int idx = it * 512 + tid;                       // 0..1023 -> row 0..63, col quad
      st.sk[m * 2 + it] = *(const float4*)(src + (rowbase + (idx >> 4)) * E + (idx & 15) * 4);
    }
  }
  const float* vp = v + (rowbase + wid * 8) * E + lane;   // lane = e, 8 key-rows per wave
#pragma unroll
  for (int i = 0; i < 8; ++i) st.sv[i] = vp[(size_t)i * E];
}

__device__ __forceinline__ void sub_commit(const SubStage& st,
    short* __restrict__ KK, short* __restrict__ Vt, int tid, int wid, int lane) {
#pragma unroll
  for (int m = 0; m < 2; ++m)
#pragma unroll
    for (int it = 0; it < 2; ++it) {
      int idx = it * 512 + tid;
      float4 f = st.sk[m * 2 + it];
      short4v h = { f2bf(f.x), f2bf(f.y), f2bf(f.z), f2bf(f.w) };
      *(short4v*)(KK + (idx >> 4) * LDK + m * 64 + (idx & 15) * 4) = h;
    }
#pragma unroll
  for (int rq = 0; rq < 2; ++rq) {
    short4v h = { f2bf(st.sv[rq*4+0]), f2bf(st.sv[rq*4+1]),
                  f2bf(st.sv[rq*4+2]), f2bf(st.sv[rq*4+3]) };
    *(short4v*)(Vt + lane * LDV + wid * 8 + rq * 4) = h;
  }
}

__device__ __forceinline__ void q_issue(float4* sq,
    const float* __restrict__ q, const float* __restrict__ qr,
    size_t rbase, int w, int wid, int li, int lg) {
  const size_t qrow = rbase + (size_t)w * 128 + wid * 16 + li;
#pragma unroll
  for (int kt = 0; kt < 4; ++kt) {
    const float* sp = (kt < 2 ? q : qr) + qrow * E + (kt & 1) * 32 + lg * 8;
    sq[kt * 2 + 0] = *(const float4*)sp;
    sq[kt * 2 + 1] = *(const float4*)(sp + 4);
  }
}

__device__ __forceinline__ void q_commit(const float4* sq, short8* aF) {
#pragma unroll
  for (int kt = 0; kt < 4; ++kt) {
    float4 f0 = sq[kt * 2], f1 = sq[kt * 2 + 1];
    short8 a;
    a[0]=f2bf(f0.x*0.125f); a[1]=f2bf(f0.y*0.125f); a[2]=f2bf(f0.z*0.125f); a[3]=f2bf(f0.w*0.125f);
    a[4]=f2bf(f1.x*0.125f); a[5]=f2bf(f1.y*0.125f); a[6]=f2bf(f1.z*0.125f); a[7]=f2bf(f1.w*0.125f);
    aF[kt] = a;
  }
}

// One block per (window, bh); 8 waves x 16 q-rows. Flash loop over four 64-key
// sub-tiles (keys win*128-128 .. win*128+127) with online softmax. Double-buffered
// sub staging: commit s+1 / issue s+2 at iteration top, one barrier per sub.
// LDS = 71680 B -> 2 blocks/CU (16 waves) for cross-block latency hiding.
__global__ __launch_bounds__(512, 4)
void la_attn(const float* __restrict__ qg, const float* __restrict__ kg,
             const float* __restrict__ qrg, const float* __restrict__ krg,
             const float* __restrict__ vg, float* __restrict__ outg) {
  extern __shared__ short smem[];

  // XCD-aware swizzle: co-locate adjacent windows (K/V overlap) on one XCD's L2
  const int lid = blockIdx.y * NWIN + blockIdx.x;        // 0..1023
  const int wl  = (lid & 7) * 128 + (lid >> 3);          // bijective remap
  const int win = wl & (NWIN - 1), bh = wl >> 5;

  const int tid = threadIdx.x;
  const int wid = tid >> 6, lane = tid & 63;
  const int li = lane & 15, lg = lane >> 4;
  const size_t rbase = (size_t)bh * T;
  const int rowb = wid * 16 + lg * 4;

  short* PW = smem + 2 * BUF_ELEMS + wid * PW_ELEMS;     // per-wave P scratch
  const int pxor_w = lg << 4;                            // write swizzle (row>>2 == lg)
  const int pxor_r = (li >> 2) << 4;                     // read swizzle (row == li)

  short8 aF[4];
  SubStage st;                                           // sub s+1 in flight

  const int s0 = (win == 0) ? 2 : 0;                     // skip padding subs
  // key-row base of sub s: win*128 - 128 + s*64  (>= 0 for s >= s0)
#define KROW(s) (rbase + (size_t)(win * 128 + ((s) - 2) * 64))

  // ---- prologue: stage sub s0 into buf0; Q; issue sub s0+1 ----
  {
    SubStage stA;
    float4 sq[8];
    sub_issue(stA, kg, krg, vg, KROW(s0), tid, wid, lane);
    q_issue(sq, qg, qrg, rbase, win, wid, li, lg);
    sub_commit(stA, smem, smem + KK_ELEMS, tid, wid, lane);
    q_commit(sq, aF);
    if (s0 + 1 < 4) sub_issue(st, kg, krg, vg, KROW(s0 + 1), tid, wid, lane);
  }
  block_sync_lds();

  float m[4], l[4];
  f32x4 O[4] = {{0,0,0,0},{0,0,0,0},{0,0,0,0},{0,0,0,0}};
#pragma unroll
  for (int r = 0; r < 4; ++r) { m[r] = -1e30f; l[r] = 0.f; }

  for (int s = s0; s < 4; ++s) {
    const int cur = (s - s0) & 1;
    short* KKc = smem + cur * BUF_ELEMS;
    short* Vtc = KKc + KK_ELEMS;

    // ---- commit staged sub s+1 into the other buffer (read-retired at last
    //      barrier); immediately issue sub s+2 (in flight across this iter) ----
    if (s + 1 < 4) {
      sub_commit(st, smem + (cur ^ 1) * BUF_ELEMS,
                 smem + (cur ^ 1) * BUF_ELEMS + KK_ELEMS, tid, wid, lane);
      if (s + 2 < 4) sub_issue(st, kg, krg, vg, KROW(s + 2), tid, wid, lane);
      asm volatile("" ::: "memory");   // pin issue point
    }

    // ---- S = [Q|Qr]·[K|Kr]^T over 64 keys: 4 ct x 4 kt MFMA ----
    f32x4 S[4];
#pragma unroll
    for (int ct = 0; ct < 4; ++ct) {
      f32x4 acc = {0.f, 0.f, 0.f, 0.f};
      const short* kb = KKc + (ct * 16 + li) * LDK + lg * 8;
#pragma unroll
      for (int kt = 0; kt < 4; ++kt)
        acc = __builtin_amdgcn_mfma_f32_16x16x32_bf16(aF[kt], *(const short8*)(kb + kt * 32), acc, 0, 0, 0);
      S[ct] = acc;
    }

    // ---- causal mask (subs 2,3 only) + online softmax update ----
    const bool causal = (s >= 2);
#pragma unroll
    for (int r = 0; r < 4; ++r) {
      const int qi = rowb + r;
      if (causal) {
#pragma unroll
        for (int ct = 0; ct < 4; ++ct) {
          int jj = (s - 2) * 64 + ct * 16 + li;     // local key pos in window
          if (jj > qi) S[ct][r] = -1e30f;
        }
      }
      float mx = fmaxf(fmaxf(S[0][r], S[1][r]), fmaxf(S[2][r], S[3][r]));
      mx = fmaxf(mx, __shfl_xor(mx, 1));
      mx = fmaxf(mx, __shfl_xor(mx, 2));
      mx = fmaxf(mx, __shfl_xor(mx, 4));
      mx = fmaxf(mx, __shfl_xor(mx, 8));
      float mn = fmaxf(m[r], mx);
      float f = __expf(m[r] - mn);                  // first sub: exp(-huge) -> 0
      float sm = 0.f;
#pragma unroll
      for (int ct = 0; ct < 4; ++ct) {
        float e = __expf(S[ct][r] - mn);
        S[ct][r] = e;
        sm += e;
      }
      sm += __shfl_xor(sm, 1);
      sm += __shfl_xor(sm, 2);
      sm += __shfl_xor(sm, 4);
      sm += __shfl_xor(sm, 8);
      l[r] = l[r] * f + sm;
      m[r] = mn;
#pragma unroll
      for (int nt = 0; nt < 4; ++nt) O[nt][r] *= f;
    }

    // ---- P -> per-wave scratch (swizzled), then PV: 2 kt x 4 nt MFMA ----
#pragma unroll
    for (int cc = 0; cc < 4; ++cc)
#pragma unroll
      for (int r = 0; r < 4; ++r)
        PW[(lg * 4 + r) * LDP + ((cc * 16 + li) ^ pxor_w)] = f2bf(S[cc][r]);
#pragma unroll
    for (int kt = 0; kt < 2; ++kt) {
      short8 aP = *(const short8*)(PW + li * LDP + ((kt * 32 + lg * 8) ^ pxor_r));
#pragma unroll
      for (int nt = 0; nt < 4; ++nt) {
        short8 b = *(const short8*)(Vtc + (nt * 16 + li) * LDV + kt * 32 + lg * 8);
        O[nt] = __builtin_amdgcn_mfma_f32_16x16x32_bf16(aP, b, O[nt], 0, 0, 0);
      }
    }

    block_sync_lds();   // all reads of buf[cur] done -> next iter may overwrite
  }

  // ---- epilogue: normalize and store ----
  float* op = outg + (rbase + (size_t)win * 128 + rowb) * E;
#pragma unroll
  for (int r = 0; r < 4; ++r) {
    float linv = 1.f / l[r];
#pragma unroll
    for (int nt = 0; nt < 4; ++nt)
      op[(size_t)r * E + nt * 16 + li] = O[nt][r] * linv;
  }
#undef KROW
}

extern "C" void kernel_launch(void* const* d_in, const int* in_sizes, int n_in,
                              void* d_out, int out_size, void* d_ws, size_t ws_size,
                              hipStream_t stream) {
  const float* q  = (const float*)d_in[0];
  const float* k  = (const float*)d_in[1];
  const float* qr = (const float*)d_in[2];
  const float* kr = (const float*)d_in[3];
  const float* v  = (const float*)d_in[4];
  float* out = (float*)d_out;
  la_attn<<<dim3(NWIN, NBH), 512, SMEM_BYTES, stream>>>(q, k, qr, kr, v, out);
}

// Round 3
// 201.322 us; speedup vs baseline: 1.0428x; 1.0428x over previous
//
#include <hip/hip_runtime.h>
#include <stdint.h>

#define T 4096
#define E 64
#define NBH 32
#define NWIN 32                 // T / 128 windows
#define LDKS 128                // [K|Kr] row stride shorts (256B row, XOR-swizzled 16B chunks)
#define LDVS 64                 // Vt row stride shorts (128B row, XOR-swizzled 16B chunks)
#define KK_ELEMS (64*LDKS)      // 8192
#define VT_ELEMS (64*LDVS)      // 4096
#define BUF_ELEMS (KK_ELEMS+VT_ELEMS)   // 12288 elems = 24576 B
#define SMEM_BYTES (2*BUF_ELEMS*2)      // 49152 B

typedef __attribute__((ext_vector_type(8))) short short8;
typedef __attribute__((ext_vector_type(4))) short short4v;
typedef __attribute__((ext_vector_type(4))) float f32x4;

__device__ __forceinline__ short f2bf(float x) {
  unsigned u = __float_as_uint(x);
  u += 0x7fffu + ((u >> 16) & 1u);   // RNE
  return (short)(u >> 16);
}

__device__ __forceinline__ unsigned cvtpk(float lo, float hi) {
  unsigned r;
  asm("v_cvt_pk_bf16_f32 %0, %1, %2" : "=v"(r) : "v"(lo), "v"(hi));
  return r;
}

// barrier without vmcnt drain (staged global loads stay in flight)
__device__ __forceinline__ void block_sync_lds() {
  asm volatile("s_waitcnt lgkmcnt(0)" ::: "memory");
  __builtin_amdgcn_s_barrier();
  asm volatile("" ::: "memory");
}

// staging registers for one 64-key sub-tile of K/Kr/V
struct SubStage { float4 sk[4]; float sv[8]; };

__device__ __forceinline__ void sub_issue(SubStage& st,
    const float* __restrict__ k, const float* __restrict__ kr,
    const float* __restrict__ v, size_t rowbase, int tid, int wid, int lane) {
#pragma unroll
  for (int m = 0; m < 2; ++m) {
    const float* src = m ? kr : k;
#pragma unroll
    for (int it = 0; it < 2; ++it) {
      int idx = it * 512 + tid;                       // row 0..63, col quad
      st.sk[m * 2 + it] = *(const float4*)(src + (rowbase + (idx >> 4)) * E + (idx & 15) * 4);
    }
  }
  const float* vp = v + (rowbase + wid * 8) * E + lane;   // lane = e, 8 key-rows per wave
#pragma unroll
  for (int i = 0; i < 8; ++i) st.sv[i] = vp[(size_t)i * E];
}

// commit with 16B-chunk XOR swizzle: chunk' = chunk ^ (row & mask)
__device__ __forceinline__ void sub_commit(const SubStage& st,
    short* __restrict__ KK, short* __restrict__ Vt, int tid, int wid, int lane) {
#pragma unroll
  for (int m = 0; m < 2; ++m)
#pragma unroll
    for (int it = 0; it < 2; ++it) {
      int idx = it * 512 + tid;
      int row = idx >> 4;
      int chunk = m * 8 + ((idx & 15) >> 1);          // 16B chunk 0..15 in 256B row
      float4 f = st.sk[m * 2 + it];
      short4v h = { f2bf(f.x), f2bf(f.y), f2bf(f.z), f2bf(f.w) };
      *(short4v*)(KK + row * LDKS + ((chunk ^ (row & 15)) << 3) + (idx & 1) * 4) = h;
    }
#pragma unroll
  for (int rq = 0; rq < 2; ++rq) {
    short4v h = { f2bf(st.sv[rq*4+0]), f2bf(st.sv[rq*4+1]),
                  f2bf(st.sv[rq*4+2]), f2bf(st.sv[rq*4+3]) };
    // row = e = lane (128B row, 8 chunks); chunk = wid, 8B half = rq
    *(short4v*)(Vt + lane * LDVS + ((wid ^ (lane & 7)) << 3) + rq * 4) = h;
  }
}

__device__ __forceinline__ void q_issue(float4* sq,
    const float* __restrict__ q, const float* __restrict__ qr,
    size_t rbase, int w, int wid, int li, int lg) {
  const size_t qrow = rbase + (size_t)w * 128 + wid * 16 + li;
#pragma unroll
  for (int kt = 0; kt < 4; ++kt) {
    const float* sp = (kt < 2 ? q : qr) + qrow * E + (kt & 1) * 32 + lg * 8;
    sq[kt * 2 + 0] = *(const float4*)sp;
    sq[kt * 2 + 1] = *(const float4*)(sp + 4);
  }
}

__device__ __forceinline__ void q_commit(const float4* sq, short8* aF) {
#pragma unroll
  for (int kt = 0; kt < 4; ++kt) {
    float4 f0 = sq[kt * 2], f1 = sq[kt * 2 + 1];
    short8 a;
    a[0]=f2bf(f0.x*0.125f); a[1]=f2bf(f0.y*0.125f); a[2]=f2bf(f0.z*0.125f); a[3]=f2bf(f0.w*0.125f);
    a[4]=f2bf(f1.x*0.125f); a[5]=f2bf(f1.y*0.125f); a[6]=f2bf(f1.z*0.125f); a[7]=f2bf(f1.w*0.125f);
    aF[kt] = a;
  }
}

// One block per (window, bh); 8 waves x 16 q-rows. Flash loop over four 64-key
// sub-tiles with online softmax, SWAPPED-OPERAND form:
//   S^T = mfma(K, Q): lane (li,lg) holds S[key=ct*16+lg*4+r][q=li] -> softmax
//   reductions are in-lane(16) + shfl_xor(16) + shfl_xor(32). P stays in
//   registers: cvt_pk_bf16 pack + 2-stage shuffle butterfly builds the PV
//   B-fragment; O^T = mfma(Vt, P^T). No P scratch, no per-r loops.
__global__ __launch_bounds__(512, 4)
void la_attn(const float* __restrict__ qg, const float* __restrict__ kg,
             const float* __restrict__ qrg, const float* __restrict__ krg,
             const float* __restrict__ vg, float* __restrict__ outg) {
  extern __shared__ short smem[];

  // XCD-aware swizzle: co-locate adjacent windows on one XCD's L2
  const int lid = blockIdx.y * NWIN + blockIdx.x;        // 0..1023
  const int wl  = (lid & 7) * 128 + (lid >> 3);          // bijective remap
  const int win = wl & (NWIN - 1), bh = wl >> 5;

  const int tid = threadIdx.x;
  const int wid = tid >> 6, lane = tid & 63;
  const int li = lane & 15, lg = lane >> 4;
  const size_t rbase = (size_t)bh * T;
  const int q_i = wid * 16 + li;                         // this lane's q row (window-local)

  short8 aF[4];
  SubStage st;                                           // sub s+1 in flight

  const int s0 = (win == 0) ? 2 : 0;                     // skip padding subs
#define KROW(s) (rbase + (size_t)(win * 128 + ((s) - 2) * 64))

  // ---- prologue: stage sub s0 into buf0; Q; issue sub s0+1 ----
  {
    SubStage stA;
    float4 sq[8];
    sub_issue(stA, kg, krg, vg, KROW(s0), tid, wid, lane);
    q_issue(sq, qg, qrg, rbase, win, wid, li, lg);
    sub_commit(stA, smem, smem + KK_ELEMS, tid, wid, lane);
    q_commit(sq, aF);
    if (s0 + 1 < 4) sub_issue(st, kg, krg, vg, KROW(s0 + 1), tid, wid, lane);
  }
  block_sync_lds();

  float m = -1e30f, l = 0.f;
  f32x4 O[4] = {{0,0,0,0},{0,0,0,0},{0,0,0,0},{0,0,0,0}};   // O^T: e=nt*16+lg*4+r, q=li

  for (int s = s0; s < 4; ++s) {
    const int cur = (s - s0) & 1;
    short* KKc = smem + cur * BUF_ELEMS;
    short* Vtc = KKc + KK_ELEMS;

    // ---- commit staged sub s+1 into other buffer; issue sub s+2 ----
    if (s + 1 < 4) {
      sub_commit(st, smem + (cur ^ 1) * BUF_ELEMS,
                 smem + (cur ^ 1) * BUF_ELEMS + KK_ELEMS, tid, wid, lane);
      if (s + 2 < 4) sub_issue(st, kg, krg, vg, KROW(s + 2), tid, wid, lane);
      asm volatile("" ::: "memory");   // pin issue point
    }

    // ---- S^T = mfma(K, Q): lane holds keys ct*16+lg*4+{0..3} for q=li ----
    f32x4 p[4];
#pragma unroll
    for (int ct = 0; ct < 4; ++ct) {
      f32x4 acc = {0.f, 0.f, 0.f, 0.f};
      const int row = ct * 16 + li;
#pragma unroll
      for (int kt = 0; kt < 4; ++kt) {
        const short* kb = KKc + row * LDKS + (((kt * 4 + lg) ^ li) << 3);
        acc = __builtin_amdgcn_mfma_f32_16x16x32_bf16(*(const short8*)kb, aF[kt], acc, 0, 0, 0);
      }
      p[ct] = acc;
    }

    // ---- causal mask (subs 2,3) + online softmax (per-lane row q=li) ----
    if (s >= 2) {
      const int joff = (s - 2) * 64 + lg * 4;
#pragma unroll
      for (int ct = 0; ct < 4; ++ct)
#pragma unroll
        for (int r = 0; r < 4; ++r)
          if (joff + ct * 16 + r > q_i) p[ct][r] = -1e30f;
    }
    float mx = -1e30f;
#pragma unroll
    for (int ct = 0; ct < 4; ++ct)
#pragma unroll
      for (int r = 0; r < 4; ++r) mx = fmaxf(mx, p[ct][r]);
    mx = fmaxf(mx, __shfl_xor(mx, 16));
    mx = fmaxf(mx, __shfl_xor(mx, 32));
    const float mn = fmaxf(m, mx);
    const float f = __expf(m - mn);                 // first sub: exp(-huge) -> 0
    float sm = 0.f;
#pragma unroll
    for (int ct = 0; ct < 4; ++ct)
#pragma unroll
      for (int r = 0; r < 4; ++r) {
        float e = __expf(p[ct][r] - mn);
        p[ct][r] = e;
        sm += e;
      }
    sm += __shfl_xor(sm, 16);
    sm += __shfl_xor(sm, 32);
    l = l * f + sm;
    m = mn;
#pragma unroll
    for (int nt = 0; nt < 4; ++nt)
#pragma unroll
      for (int r = 0; r < 4; ++r) O[nt][r] *= f;

    // ---- pack P^T to bf16 pairs: W0/W1[ct] = keys ct*16+lg*4+{0,1}/{2,3} ----
    unsigned W0[4], W1[4];
#pragma unroll
    for (int ct = 0; ct < 4; ++ct) {
      W0[ct] = cvtpk(p[ct][0], p[ct][1]);
      W1[ct] = cvtpk(p[ct][2], p[ct][3]);
    }

    // ---- PV: per kt, butterfly-redistribute P^T into B-fragment, then
    //      O^T += mfma(Vt, P^T). Dest lane (li,lg) needs keys kt*32+lg*8+{0..7}
    //      = pairs (ct*=2kt+(lg>>1), src-lg sA=(lg&1)*2 and sA+1). ----
    const bool lowhalf = (lg < 2);
    const bool sendR = (lg == 0) | (lg == 3);
#pragma unroll
    for (int kt = 0; kt < 2; ++kt) {
      const int cA = kt * 2, cB = cA + 1;
      unsigned P0 = lowhalf ? W0[cB] : W0[cA];      // payload the other half needs
      unsigned P1 = lowhalf ? W1[cB] : W1[cA];
      unsigned R0 = __shfl_xor(P0, 32);             // lg^2 exchange
      unsigned R1 = __shfl_xor(P1, 32);
      unsigned L0 = lowhalf ? W0[cA] : W0[cB];      // own-half local pair
      unsigned L1 = lowhalf ? W1[cA] : W1[cB];
      unsigned S0 = sendR ? R0 : L0;
      unsigned S1 = sendR ? R1 : L1;
      unsigned T0 = __shfl_xor(S0, 16);             // lg^1 exchange
      unsigned T1 = __shfl_xor(S1, 16);
      // assemble: first pair (keys +0..3), second pair (keys +4..7)
      unsigned F0 = (lg == 0) ? L0 : ((lg == 2) ? R0 : T0);
      unsigned F1 = (lg == 0) ? L1 : ((lg == 2) ? R1 : T1);
      unsigned G0 = (lg == 1) ? R0 : ((lg == 3) ? L0 : T0);
      unsigned G1 = (lg == 1) ? R1 : ((lg == 3) ? L1 : T1);
      union { unsigned u[4]; short8 s; } bu;
      bu.u[0] = F0; bu.u[1] = F1; bu.u[2] = G0; bu.u[3] = G1;
      const short8 bP = bu.s;
#pragma unroll
      for (int nt = 0; nt < 4; ++nt) {
        const short* vb = Vtc + (nt * 16 + li) * LDVS + (((kt * 4 + lg) ^ (li & 7)) << 3);
        O[nt] = __builtin_amdgcn_mfma_f32_16x16x32_bf16(*(const short8*)vb, bP, O[nt], 0, 0, 0);
      }
    }

    block_sync_lds();   // all reads of buf[cur] done -> next iter may overwrite
  }

  // ---- epilogue: normalize and store O^T (lane: q=li, e=nt*16+lg*4+{0..3}) ----
  const float linv = 1.f / l;
  float* op = outg + (rbase + (size_t)win * 128 + wid * 16 + li) * E + lg * 4;
#pragma unroll
  for (int nt = 0; nt < 4; ++nt) {
    float4 o = { O[nt][0] * linv, O[nt][1] * linv, O[nt][2] * linv, O[nt][3] * linv };
    *(float4*)(op + nt * 16) = o;
  }
#undef KROW
}

extern "C" void kernel_launch(void* const* d_in, const int* in_sizes, int n_in,
                              void* d_out, int out_size, void* d_ws, size_t ws_size,
                              hipStream_t stream) {
  const float* q  = (const float*)d_in[0];
  const float* k  = (const float*)d_in[1];
  const float* qr = (const float*)d_in[2];
  const float* kr = (const float*)d_in[3];
  const float* v  = (const float*)d_in[4];
  float* out = (float*)d_out;
  la_attn<<<dim3(NWIN, NBH), 512, SMEM_BYTES, stream>>>(q, k, qr, kr, v, out);
}